// Round 4
// baseline (216.114 us; speedup 1.0000x reference)
//
#include <hip/hip_runtime.h>

// Problem constants
#define NPAR   8192      // parents
#define NCH    65536     // children = NPAR*8
#define RES    32
#define EPS    1e-5f

typedef __attribute__((ext_vector_type(8))) short short8;
typedef __attribute__((ext_vector_type(4))) float floatx4;

__device__ __forceinline__ unsigned short f2bf(float f) {
    union { float f; unsigned u; } v; v.f = f;
    unsigned r = v.u + 0x7fffu + ((v.u >> 16) & 1u);   // RNE
    return (unsigned short)(r >> 16);
}
__device__ __forceinline__ float bf2f(unsigned short b) {
    union { unsigned u; float f; } v; v.u = ((unsigned)b) << 16;
    return v.f;
}
// async 16B global->LDS: per-lane global addr, wave-uniform LDS base (+lane*16)
__device__ __forceinline__ void glds16(const void* g, void* l) {
    __builtin_amdgcn_global_load_lds(
        (__attribute__((address_space(1))) const void*)g,
        (__attribute__((address_space(3))) void*)l, 16, 0, 0);
}
// parent-grid tap index for (child-offset o, slot s): e_a = o_a + s_a - 1
__device__ __forceinline__ int k27_of(int o, int s) {
    return (((o >> 2) & 1) + ((s >> 2) & 1)) * 9 +
           (((o >> 1) & 1) + ((s >> 1) & 1)) * 3 +
           ((o & 1) + (s & 1));
}
// For child offset o and fine tap k (0..26): parent tap + slot-base row offset.
// e_a = o_a + d_a, d_a = k_a - 1; parent tap axis = (e_a>>1)+1, slot bit = e_a&1.
__device__ __forceinline__ void tap_ps(int o, int k, int& ptap, int& slotBase) {
    int ex = ((o >> 2) & 1) + k / 9 - 1;
    int ey = ((o >> 1) & 1) + (k / 3) % 3 - 1;
    int ez = (o & 1) + k % 3 - 1;
    ptap = ((ex >> 1) + 1) * 9 + ((ey >> 1) + 1) * 3 + ((ez >> 1) + 1);
    slotBase = (((ex & 1) << 2) + ((ey & 1) << 1) + (ez & 1)) * NPAR;
}
// fine-tap d-list per axis for (o,s) folding
__device__ __forceinline__ void axis_dlist(int o, int s, int* d, int& n) {
    if (o == 0) { if (s == 0) { d[0] = -1; n = 1; } else { d[0] = 0; d[1] = 1; n = 2; } }
    else        { if (s == 0) { d[0] = -1; d[1] = 0; n = 2; } else { d[0] = 1; n = 1; } }
}

// ---------------------------------------------------------------------------
// K1: blocks [0,32) scatter parents into grid32; blocks [32,288) GN1 stats.
__global__ void k1_kernel(const int* __restrict__ coords, int* __restrict__ grid32,
                          const float* __restrict__ x, float* __restrict__ sum,
                          float* __restrict__ sq) {
    int b = blockIdx.x;
    int t = threadIdx.x;
    if (b < 32) {
        int p = b * 256 + t;
        grid32[(coords[p*3] << 10) + (coords[p*3+1] << 5) + coords[p*3+2]] = p;
    } else {
        __shared__ float s_sum[32], s_sq[32];
        if (t < 32) { s_sum[t] = 0.0f; s_sq[t] = 0.0f; }
        __syncthreads();
        const float4* x4 = (const float4*)x;
        int total = NPAR * 32;
        int idx0 = (b - 32) * 256 + t;
        int g = idx0 & 31;
        float ls = 0.0f, lq = 0.0f;
        for (int idx = idx0; idx < total; idx += 256 * 256) {
            float4 v = x4[idx];
            ls += v.x + v.y + v.z + v.w;
            lq += v.x * v.x + v.y * v.y + v.z * v.z + v.w * v.w;
        }
        atomicAdd(&s_sum[g], ls);
        atomicAdd(&s_sq[g], lq);
        __syncthreads();
        if (t < 32) { atomicAdd(&sum[t], s_sum[t]); atomicAdd(&sq[t], s_sq[t]); }
    }
}

// ---------------------------------------------------------------------------
// K2, 1016 blocks: pidx27 (per-parent gathers) / W2 pack / W1 fold+pack / GN1
__global__ void k2_kernel(const int* __restrict__ coords, const int* __restrict__ grid32,
                          int* __restrict__ pidx27,
                          const float* __restrict__ W1, const float* __restrict__ W2,
                          unsigned short* __restrict__ Wc1f, unsigned short* __restrict__ Wp2,
                          const float* __restrict__ x, const float* __restrict__ sum,
                          const float* __restrict__ sq, const float* __restrict__ gamma,
                          const float* __restrict__ beta, unsigned short* __restrict__ y) {
    int b = blockIdx.x;
    if (b < 32) {
        // Per-parent: 27 grid32 gathers -> pidx27 (coalesced int writes).
        int p = b * 256 + threadIdx.x;      // 8192 parents
        int cx = coords[p*3], cy = coords[p*3+1], cz = coords[p*3+2];
#pragma unroll
        for (int k = 0; k < 27; ++k) {
            int nx = cx + k / 9 - 1, ny = cy + (k / 3) % 3 - 1, nz = cz + k % 3 - 1;
            int r = -1;
            if ((unsigned)nx < 32u && (unsigned)ny < 32u && (unsigned)nz < 32u) {
                int g = grid32[(nx << 10) + (ny << 5) + nz];
                if ((unsigned)g < (unsigned)NPAR) r = g;
            }
            pidx27[k * NPAR + p] = r;
        }
    } else if (b < 248) {
        int rem = (b - 32) * 256 + threadIdx.x;   // < 55296
        int lane = rem & 63;
        int ks   = (rem >> 6) & 3;
        int nb   = (rem >> 8) & 7;
        int tap  = rem >> 11;                       // 0..26
        int n  = nb * 16 + (lane & 15);
        int k0 = ks * 32 + (lane >> 4) * 8;
        unsigned short v[8];
#pragma unroll
        for (int j = 0; j < 8; ++j) v[j] = f2bf(W2[tap * 16384 + (k0 + j) * 128 + n]);
        uint4 pk;
        pk.x = (unsigned)v[0] | ((unsigned)v[1] << 16);
        pk.y = (unsigned)v[2] | ((unsigned)v[3] << 16);
        pk.z = (unsigned)v[4] | ((unsigned)v[5] << 16);
        pk.w = (unsigned)v[6] | ((unsigned)v[7] << 16);
        *(uint4*)&Wp2[(long)rem * 8] = pk;
    } else if (b < 760) {
        int rem = (b - 248) * 256 + threadIdx.x;   // < 131072
        int lane  = rem & 63;
        int ks    = (rem >> 6) & 3;
        int nb    = (rem >> 8) & 7;
        int combo = rem >> 11;                      // 0..63 = o*8+s
        int o = combo >> 3, s = combo & 7;
        int n  = nb * 16 + (lane & 15);
        int k0 = ks * 32 + (lane >> 4) * 8;
        int d0[2], d1[2], d2[2], n0, n1, n2;
        axis_dlist((o >> 2) & 1, (s >> 2) & 1, d0, n0);
        axis_dlist((o >> 1) & 1, (s >> 1) & 1, d1, n1);
        axis_dlist(o & 1,        s & 1,        d2, n2);
        unsigned short v[8];
#pragma unroll
        for (int j = 0; j < 8; ++j) {
            float acc = 0.0f;
            for (int a = 0; a < n0; ++a)
                for (int bb = 0; bb < n1; ++bb)
                    for (int cc = 0; cc < n2; ++cc) {
                        int kk = (d0[a] + 1) * 9 + (d1[bb] + 1) * 3 + (d2[cc] + 1);
                        acc += W1[kk * 16384 + (k0 + j) * 128 + n];
                    }
            v[j] = f2bf(acc);
        }
        uint4 pk;
        pk.x = (unsigned)v[0] | ((unsigned)v[1] << 16);
        pk.y = (unsigned)v[2] | ((unsigned)v[3] << 16);
        pk.z = (unsigned)v[4] | ((unsigned)v[5] << 16);
        pk.w = (unsigned)v[6] | ((unsigned)v[7] << 16);
        *(uint4*)&Wc1f[(long)rem * 8] = pk;
    } else {
        const float4* x4 = (const float4*)x;
        uint2* y2 = (uint2*)y;
        const float4* g4 = (const float4*)gamma;
        const float4* b4 = (const float4*)beta;
        float cnt = (float)NPAR * 4.0f;
        int total = NPAR * 32;
        for (int idx = (b - 760) * 256 + threadIdx.x; idx < total; idx += 256 * 256) {
            int c4 = idx & 31;
            float mean = sum[c4] / cnt;
            float var = sq[c4] / cnt - mean * mean;
            float rstd = rsqrtf(var + EPS);
            float4 v = x4[idx];
            float4 gm = g4[c4];
            float4 bt = b4[c4];
            float a[4] = {v.x, v.y, v.z, v.w};
            float gg[4] = {gm.x, gm.y, gm.z, gm.w};
            float bb[4] = {bt.x, bt.y, bt.z, bt.w};
            unsigned short o[4];
#pragma unroll
            for (int i = 0; i < 4; ++i) {
                float tv = (a[i] - mean) * rstd * gg[i] + bb[i];
                o[i] = f2bf(tv / (1.0f + __expf(-tv)));
            }
            uint2 pk;
            pk.x = (unsigned)o[0] | ((unsigned)o[1] << 16);
            pk.y = (unsigned)o[2] | ((unsigned)o[3] << 16);
            y2[idx] = pk;
        }
    }
}

// ---------------------------------------------------------------------------
// bf16 in -> bf16 out, in place (GN2); layout-agnostic elementwise
__global__ void gn_apply_bf16_kernel(unsigned short* __restrict__ x,
                                     const float* __restrict__ sum, const float* __restrict__ sq,
                                     const float* __restrict__ gamma, const float* __restrict__ beta,
                                     int nrows) {
    uint2* x2 = (uint2*)x;
    const float4* g4 = (const float4*)gamma;
    const float4* b4 = (const float4*)beta;
    float cnt = (float)nrows * 4.0f;
    int total = nrows * 32;
    for (int idx = blockIdx.x * blockDim.x + threadIdx.x; idx < total;
         idx += gridDim.x * blockDim.x) {
        int c4 = idx & 31;
        float mean = sum[c4] / cnt;
        float var = sq[c4] / cnt - mean * mean;
        float rstd = rsqrtf(var + EPS);
        uint2 pk = x2[idx];
        float a[4] = {bf2f((unsigned short)(pk.x & 0xffff)), bf2f((unsigned short)(pk.x >> 16)),
                      bf2f((unsigned short)(pk.y & 0xffff)), bf2f((unsigned short)(pk.y >> 16))};
        float4 gm = g4[c4];
        float4 bt = b4[c4];
        float gg[4] = {gm.x, gm.y, gm.z, gm.w};
        float bb[4] = {bt.x, bt.y, bt.z, bt.w};
        unsigned short o[4];
#pragma unroll
        for (int i = 0; i < 4; ++i) {
            float tv = (a[i] - mean) * rstd * gg[i] + bb[i];
            o[i] = f2bf(tv / (1.0f + __expf(-tv)));
        }
        pk.x = (unsigned)o[0] | ((unsigned)o[1] << 16);
        pk.y = (unsigned)o[2] | ((unsigned)o[3] << 16);
        x2[idx] = pk;
    }
}

// ---------------------------------------------------------------------------
// Shared MFMA helpers.
//
// LDS A layout (per buffer): [grp(8)][ks(4)][r16(16)][cch(4)][8 shorts].
// Bank-conflict fix (verified: SQ_LDS_BANK_CONFLICT 3.54M -> 0): the 16B
// chunk stored at (r16, cch) holds source channels ks*32 + (cch^((r16>>1)&3))*8
// — XOR applied on the GLOBAL source address (global_load_lds writes
// linearly), undone on the ds_read side (swz = quad ^ ((l16>>1)&3)).
__device__ __forceinline__ void mfma_phase(
    const unsigned short* __restrict__ Abuf, short8 (&bfr)[4][4],
    floatx4 (&acc)[4][4], int wm, int aswz) {
#pragma unroll
    for (int ks = 0; ks < 4; ++ks) {
        short8 afr[4];
#pragma unroll
        for (int mt = 0; mt < 4; ++mt)
            afr[mt] = *(const short8*)&Abuf[(wm << 13) + (mt << 11) + (ks << 9) + aswz];
#pragma unroll
        for (int mt = 0; mt < 4; ++mt)
#pragma unroll
            for (int nt = 0; nt < 4; ++nt)
                acc[mt][nt] = __builtin_amdgcn_mfma_f32_16x16x32_bf16(
                    afr[mt], bfr[nt][ks], acc[mt][nt], 0, 0, 0);
    }
}
__device__ __forceinline__ void loadB(const unsigned short* __restrict__ Wtap,
                                      short8 (&bfr)[4][4], int wn, int lane) {
#pragma unroll
    for (int nt = 0; nt < 4; ++nt)
#pragma unroll
        for (int ks = 0; ks < 4; ++ks)
            bfr[nt][ks] = *(const short8*)&Wtap[(((wn * 4 + nt) << 2) + ks) * 512 + (lane << 3)];
}
__device__ __forceinline__ void stageA(const unsigned short* __restrict__ Ag,
                                       int iv0, int iv1, const unsigned short* zsrc,
                                       unsigned short* __restrict__ buf,
                                       int base0, int base1, int cchOff) {
    const unsigned short* g0 = (iv0 >= 0) ? Ag + (long)iv0 * 128 : zsrc;
    const unsigned short* g1 = (iv1 >= 0) ? Ag + (long)iv1 * 128 : zsrc;
#pragma unroll
    for (int i = 0; i < 4; ++i) glds16(g0 + i * 32 + cchOff, &buf[base0 + i * 512]);
#pragma unroll
    for (int i = 0; i < 4; ++i) glds16(g1 + i * 32 + cchOff, &buf[base1 + i * 512]);
}

// ---------------------------------------------------------------------------
// CONV1 FOLDED — 2x-unrolled slot loop, ping-pong B register sets (bA/bB, no
// copies) so the compiler must keep the prefetched B set live across the
// barrier.
__global__ void __launch_bounds__(256, 2) conv1_fold_kernel(
    const unsigned short* __restrict__ Ag, const unsigned short* __restrict__ Wc1f,
    const float* __restrict__ bias, const int* __restrict__ pidx27,
    unsigned short* __restrict__ outp, const float* __restrict__ zpage,
    float* __restrict__ gsum, float* __restrict__ gsq) {
    __shared__ unsigned short A_lds[2][16384];   // 2 x 32 KB

    int t = threadIdx.x;
    int o  = blockIdx.x & 7;
    int P0 = (blockIdx.x >> 3) << 7;            // 128 parents per block
    const unsigned short* Wb = Wc1f + ((long)o << 17);
    int wv = t >> 6, lane = t & 63, quad = lane >> 4, l16 = lane & 15;
    int wm = wv & 1, wn = wv >> 1;
    int r16 = lane >> 2, cch = lane & 3;
    int c0 = wv * 2, c1 = wv * 2 + 1;
    int row0 = ((c0 >> 2) << 6) + ((c0 & 3) << 4) + r16;
    int row1 = ((c1 >> 2) << 6) + ((c1 & 3) << 4) + r16;
    int base0 = ((c0 >> 2) << 13) + ((c0 & 3) << 11);
    int base1 = ((c1 >> 2) << 13) + ((c1 & 3) << 11);
    int cchOff = (cch ^ ((r16 >> 1) & 3)) << 3;            // swizzled source chunk
    int aswz = (l16 << 5) + ((quad ^ ((l16 >> 1) & 3)) << 3);  // swizzled read
    const unsigned short* zsrc = (const unsigned short*)zpage;

    floatx4 acc[4][4];
#pragma unroll
    for (int mt = 0; mt < 4; ++mt)
#pragma unroll
        for (int nt = 0; nt < 4; ++nt)
            acc[mt][nt] = (floatx4){0.f, 0.f, 0.f, 0.f};
    short8 bA[4][4], bB[4][4];

    // ---- prolog: slot 0 A -> buf0, slot 0 B -> bA
    stageA(Ag, pidx27[k27_of(o, 0) * NPAR + P0 + row0],
               pidx27[k27_of(o, 0) * NPAR + P0 + row1], zsrc, A_lds[0], base0, base1, cchOff);
    loadB(Wb, bA, wn, lane);
    int nv0 = pidx27[k27_of(o, 1) * NPAR + P0 + row0];
    int nv1 = pidx27[k27_of(o, 1) * NPAR + P0 + row1];
    __syncthreads();

#pragma unroll 1
    for (int s = 0; s < 8; s += 2) {
        // phase A: slot s from buf0/bA; stage slot s+1 -> buf1, B(s+1) -> bB
        stageA(Ag, nv0, nv1, zsrc, A_lds[1], base0, base1, cchOff);
        loadB(Wb + ((long)(s + 1) << 14), bB, wn, lane);
        if (s + 2 < 8) {
            nv0 = pidx27[k27_of(o, s + 2) * NPAR + P0 + row0];
            nv1 = pidx27[k27_of(o, s + 2) * NPAR + P0 + row1];
        }
        mfma_phase(A_lds[0], bA, acc, wm, aswz);
        __syncthreads();
        // phase B: slot s+1 from buf1/bB; stage slot s+2 -> buf0, B(s+2) -> bA
        if (s + 2 < 8) {
            stageA(Ag, nv0, nv1, zsrc, A_lds[0], base0, base1, cchOff);
            loadB(Wb + ((long)(s + 2) << 14), bA, wn, lane);
            if (s + 3 < 8) {
                nv0 = pidx27[k27_of(o, s + 3) * NPAR + P0 + row0];
                nv1 = pidx27[k27_of(o, s + 3) * NPAR + P0 + row1];
            }
        }
        mfma_phase(A_lds[1], bB, acc, wm, aswz);
        __syncthreads();
    }

    // ---- epilogue: coalesced bf16 store at row o*NPAR + p, fused GN2 stats
    float s_[4] = {0.f, 0.f, 0.f, 0.f}, q_[4] = {0.f, 0.f, 0.f, 0.f};
#pragma unroll
    for (int nt = 0; nt < 4; ++nt) {
        int col = wn * 64 + nt * 16 + l16;
        float bv = bias[col];
#pragma unroll
        for (int mt = 0; mt < 4; ++mt) {
#pragma unroll
            for (int r = 0; r < 4; ++r) {
                int prow = wm * 64 + mt * 16 + quad * 4 + r;
                long R = (long)o * NPAR + P0 + prow;
                float v = acc[mt][nt][r] + bv;
                unsigned short u = f2bf(v);
                outp[R * 128 + col] = u;
                float vr = bf2f(u);
                s_[nt] += vr;
                q_[nt] += vr * vr;
            }
        }
    }
    float* sred = (float*)A_lds;   // safe: loop's trailing barrier passed
    if (t < 64) sred[t] = 0.0f;
    __syncthreads();
#pragma unroll
    for (int nt = 0; nt < 4; ++nt) {
        int g = (wn * 64 + nt * 16 + l16) >> 2;
        atomicAdd(&sred[g], s_[nt]);
        atomicAdd(&sred[32 + g], q_[nt]);
    }
    __syncthreads();
    if (t < 32) { atomicAdd(&gsum[t], sred[t]); atomicAdd(&gsq[t], sred[32 + t]); }
}

// ---------------------------------------------------------------------------
// CONV2 — (o,p) block form: blocks = (o, 128-parent tile), 27 fine taps.
// A-source row = slot(o,k)*NPAR + pidx27[ptap(o,k)*NPAR + p]  (h1b is (o,p)).
// idx_tab is gone: ptap/slot are uniform per (o,tap) — SGPR math.
__global__ void __launch_bounds__(256, 2) conv2_kernel(
    const unsigned short* __restrict__ Ag, const unsigned short* __restrict__ Wp,
    const float* __restrict__ bias, const int* __restrict__ pidx27,
    const float* __restrict__ resid, float* __restrict__ outp,
    const float* __restrict__ zpage) {
    __shared__ unsigned short A_lds[2][16384];   // 2 x 32 KB

    int t = threadIdx.x;
    int o  = blockIdx.x & 7;
    int P0 = (blockIdx.x >> 3) << 7;            // 128 parents per block
    int wv = t >> 6, lane = t & 63, quad = lane >> 4, l16 = lane & 15;
    int wm = wv & 1, wn = wv >> 1;
    int r16 = lane >> 2, cch = lane & 3;
    int c0 = wv * 2, c1 = wv * 2 + 1;
    int row0 = ((c0 >> 2) << 6) + ((c0 & 3) << 4) + r16;
    int row1 = ((c1 >> 2) << 6) + ((c1 & 3) << 4) + r16;
    int base0 = ((c0 >> 2) << 13) + ((c0 & 3) << 11);
    int base1 = ((c1 >> 2) << 13) + ((c1 & 3) << 11);
    int cchOff = (cch ^ ((r16 >> 1) & 3)) << 3;            // swizzled source chunk
    int aswz = (l16 << 5) + ((quad ^ ((l16 >> 1) & 3)) << 3);  // swizzled read
    const unsigned short* zsrc = (const unsigned short*)zpage;

    floatx4 acc[4][4];
#pragma unroll
    for (int mt = 0; mt < 4; ++mt)
#pragma unroll
        for (int nt = 0; nt < 4; ++nt)
            acc[mt][nt] = (floatx4){0.f, 0.f, 0.f, 0.f};
    short8 bA[4][4], bB[4][4];

    // ---- prolog: tap 0 A -> buf0, tap 0 B -> bA; prefetch tap-1 indices
    {
        int pt, sb; tap_ps(o, 0, pt, sb);
        int r0 = pidx27[pt * NPAR + P0 + row0];
        int r1 = pidx27[pt * NPAR + P0 + row1];
        stageA(Ag, r0 >= 0 ? sb + r0 : -1, r1 >= 0 ? sb + r1 : -1,
               zsrc, A_lds[0], base0, base1, cchOff);
    }
    loadB(Wp, bA, wn, lane);
    int nv0, nv1;
    {
        int pt, sb; tap_ps(o, 1, pt, sb);
        int r0 = pidx27[pt * NPAR + P0 + row0];
        int r1 = pidx27[pt * NPAR + P0 + row1];
        nv0 = r0 >= 0 ? sb + r0 : -1;
        nv1 = r1 >= 0 ? sb + r1 : -1;
    }
    __syncthreads();

#pragma unroll 1
    for (int k = 0; k < 27; k += 2) {
        // phase A: tap k from buf0/bA
        if (k + 1 < 27) {
            stageA(Ag, nv0, nv1, zsrc, A_lds[1], base0, base1, cchOff);
            loadB(Wp + ((long)(k + 1) << 14), bB, wn, lane);
            if (k + 2 < 27) {
                int pt, sb; tap_ps(o, k + 2, pt, sb);
                int r0 = pidx27[pt * NPAR + P0 + row0];
                int r1 = pidx27[pt * NPAR + P0 + row1];
                nv0 = r0 >= 0 ? sb + r0 : -1;
                nv1 = r1 >= 0 ? sb + r1 : -1;
            }
        }
        mfma_phase(A_lds[0], bA, acc, wm, aswz);
        __syncthreads();
        // phase B: tap k+1 from buf1/bB
        if (k + 1 < 27) {
            if (k + 2 < 27) {
                stageA(Ag, nv0, nv1, zsrc, A_lds[0], base0, base1, cchOff);
                loadB(Wp + ((long)(k + 2) << 14), bA, wn, lane);
                if (k + 3 < 27) {
                    int pt, sb; tap_ps(o, k + 3, pt, sb);
                    int r0 = pidx27[pt * NPAR + P0 + row0];
                    int r1 = pidx27[pt * NPAR + P0 + row1];
                    nv0 = r0 >= 0 ? sb + r0 : -1;
                    nv1 = r1 >= 0 ? sb + r1 : -1;
                }
            }
            mfma_phase(A_lds[1], bB, acc, wm, aswz);
            __syncthreads();
        }
    }

    // ---- epilogue: out row = p*8 + o (dense 512B rows); resid[p] contiguous
#pragma unroll
    for (int nt = 0; nt < 4; ++nt) {
        int col = wn * 64 + nt * 16 + l16;
        float bv = bias[col];
#pragma unroll
        for (int mt = 0; mt < 4; ++mt) {
#pragma unroll
            for (int r = 0; r < 4; ++r) {
                int prow = wm * 64 + mt * 16 + quad * 4 + r;
                long p = (long)P0 + prow;
                float v = acc[mt][nt][r] + bv + resid[p * 128 + col];
                outp[(p * 8 + o) * 128 + col] = v;
            }
        }
    }
}

// ---------------------------------------------------------------------------
extern "C" void kernel_launch(void* const* d_in, const int* in_sizes, int n_in,
                              void* d_out, int out_size, void* d_ws, size_t ws_size,
                              hipStream_t stream) {
    const float* feats  = (const float*)d_in[0];
    const float* gamma1 = (const float*)d_in[1];
    const float* beta1  = (const float*)d_in[2];
    const float* W1     = (const float*)d_in[3];
    const float* b1     = (const float*)d_in[4];
    const float* gamma2 = (const float*)d_in[5];
    const float* beta2  = (const float*)d_in[6];
    const float* W2     = (const float*)d_in[7];
    const float* b2     = (const float*)d_in[8];
    const int*   coords = (const int*)d_in[9];
    float* out = (float*)d_out;   // 65536 x 128 fp32 (written only by conv2)

    char* ws = (char*)d_ws;
    unsigned short* h0b  = (unsigned short*)(ws);                    // 2 MB
    unsigned short* h1b  = (unsigned short*)(ws + (2u << 20));       // 16 MB, (o,p) layout
    unsigned short* Wc1f = (unsigned short*)(ws + (18u << 20));      // 2 MB
    unsigned short* Wp2  = (unsigned short*)(ws + (20u << 20));      // 864 KB
    int*   grid32        = (int*)  (ws + (21u << 20));               // 128 KB
    float* stats         = (float*)(ws + (21u << 20) + 131072);      // 512 B
    float* zpage         = (float*)(ws + (21u << 20) + 131072 + 512);// 512 B
    int*   pidx27        = (int*)  (ws + (22u << 20));               // 864 KB

    // zero stats (128 f) + zpage (128 f) in one async memset
    hipMemsetAsync(stats, 0, 1024, stream);

    k1_kernel<<<288, 256, 0, stream>>>(coords, grid32, feats, stats + 0, stats + 32);
    k2_kernel<<<1016, 256, 0, stream>>>(coords, grid32, pidx27,
                                        W1, W2, Wc1f, Wp2,
                                        feats, stats + 0, stats + 32, gamma1, beta1, h0b);

    // conv1 folded -> bf16 h1b in (o,p) layout + fused GN2 stats
    conv1_fold_kernel<<<8 * (NPAR / 128), 256, 0, stream>>>(h0b, Wc1f, b1, pidx27,
                                                            h1b, zpage,
                                                            stats + 64, stats + 96);

    gn_apply_bf16_kernel<<<1024, 256, 0, stream>>>(h1b, stats + 64, stats + 96, gamma2, beta2, NCH);

    // conv2 (o,p form; 27 taps over children via pidx27) -> fp32 out + residual
    conv2_kernel<<<8 * (NPAR / 128), 256, 0, stream>>>(h1b, Wp2, b2, pidx27,
                                                       feats, out, zpage);
}

// Round 5
// 201.735 us; speedup vs baseline: 1.0713x; 1.0713x over previous
//
#include <hip/hip_runtime.h>

// Problem constants
#define NPAR   8192      // parents
#define NCH    65536     // children = NPAR*8
#define RES    32
#define EPS    1e-5f

typedef __attribute__((ext_vector_type(8))) short short8;
typedef __attribute__((ext_vector_type(4))) float floatx4;

__device__ __forceinline__ unsigned short f2bf(float f) {
    union { float f; unsigned u; } v; v.f = f;
    unsigned r = v.u + 0x7fffu + ((v.u >> 16) & 1u);   // RNE
    return (unsigned short)(r >> 16);
}
__device__ __forceinline__ float bf2f(unsigned short b) {
    union { unsigned u; float f; } v; v.u = ((unsigned)b) << 16;
    return v.f;
}
// async 16B global->LDS: per-lane global addr, wave-uniform LDS base (+lane*16)
__device__ __forceinline__ void glds16(const void* g, void* l) {
    __builtin_amdgcn_global_load_lds(
        (__attribute__((address_space(1))) const void*)g,
        (__attribute__((address_space(3))) void*)l, 16, 0, 0);
}
// parent-grid tap index for (child-offset o, slot s): e_a = o_a + s_a - 1
__device__ __forceinline__ int k27_of(int o, int s) {
    return (((o >> 2) & 1) + ((s >> 2) & 1)) * 9 +
           (((o >> 1) & 1) + ((s >> 1) & 1)) * 3 +
           ((o & 1) + (s & 1));
}
// fine-tap d-list per axis for (o,s) folding
__device__ __forceinline__ void axis_dlist(int o, int s, int* d, int& n) {
    if (o == 0) { if (s == 0) { d[0] = -1; n = 1; } else { d[0] = 0; d[1] = 1; n = 2; } }
    else        { if (s == 0) { d[0] = -1; d[1] = 0; n = 2; } else { d[0] = 1; n = 1; } }
}

// ---------------------------------------------------------------------------
// K1: blocks [0,32) scatter parents into grid32; blocks [32,288) GN1 stats.
__global__ void k1_kernel(const int* __restrict__ coords, int* __restrict__ grid32,
                          const float* __restrict__ x, float* __restrict__ sum,
                          float* __restrict__ sq) {
    int b = blockIdx.x;
    int t = threadIdx.x;
    if (b < 32) {
        int p = b * 256 + t;
        grid32[(coords[p*3] << 10) + (coords[p*3+1] << 5) + coords[p*3+2]] = p;
    } else {
        __shared__ float s_sum[32], s_sq[32];
        if (t < 32) { s_sum[t] = 0.0f; s_sq[t] = 0.0f; }
        __syncthreads();
        const float4* x4 = (const float4*)x;
        int total = NPAR * 32;
        int idx0 = (b - 32) * 256 + t;
        int g = idx0 & 31;
        float ls = 0.0f, lq = 0.0f;
        for (int idx = idx0; idx < total; idx += 256 * 256) {
            float4 v = x4[idx];
            ls += v.x + v.y + v.z + v.w;
            lq += v.x * v.x + v.y * v.y + v.z * v.z + v.w * v.w;
        }
        atomicAdd(&s_sum[g], ls);
        atomicAdd(&s_sq[g], lq);
        __syncthreads();
        if (t < 32) { atomicAdd(&sum[t], s_sum[t]); atomicAdd(&sq[t], s_sq[t]); }
    }
}

// ---------------------------------------------------------------------------
// K2, 1016 blocks: idx_tab+pidx27 (per-parent) / W2 pack / W1 fold+pack / GN1
__global__ void k2_kernel(const int* __restrict__ coords, const int* __restrict__ grid32,
                          int* __restrict__ idx_tab, int* __restrict__ pidx27,
                          const float* __restrict__ W1, const float* __restrict__ W2,
                          unsigned short* __restrict__ Wc1f, unsigned short* __restrict__ Wp2,
                          const float* __restrict__ x, const float* __restrict__ sum,
                          const float* __restrict__ sq, const float* __restrict__ gamma,
                          const float* __restrict__ beta, unsigned short* __restrict__ y) {
    int b = blockIdx.x;
    if (b < 32) {
        // Per-parent: 27 grid32 gathers -> registers (fully unrolled, static
        // indexing only), emit pidx27 (27 ints) + idx_tab (27 taps x 8
        // children, coalesced int4 writes).  Child fine tap d at child o:
        // e=o+d per axis -> parent tap (e>>1), slot bit (e&1).
        int p = b * 256 + threadIdx.x;      // 8192 parents
        int cx = coords[p*3], cy = coords[p*3+1], cz = coords[p*3+2];
        int r27[27];
#pragma unroll
        for (int k = 0; k < 27; ++k) {
            int nx = cx + k / 9 - 1, ny = cy + (k / 3) % 3 - 1, nz = cz + k % 3 - 1;
            int r = -1;
            if ((unsigned)nx < 32u && (unsigned)ny < 32u && (unsigned)nz < 32u) {
                int g = grid32[(nx << 10) + (ny << 5) + nz];
                if ((unsigned)g < (unsigned)NPAR) r = g;
            }
            r27[k] = r;
            pidx27[k * NPAR + p] = r;
        }
#pragma unroll
        for (int k = 0; k < 27; ++k) {
            const int dx = k / 9 - 1, dy = (k / 3) % 3 - 1, dz = k % 3 - 1;
            int v[8];
#pragma unroll
            for (int o = 0; o < 8; ++o) {
                const int ex = ((o >> 2) & 1) + dx;
                const int ey = ((o >> 1) & 1) + dy;
                const int ez = (o & 1) + dz;
                const int ptap = ((ex >> 1) + 1) * 9 + ((ey >> 1) + 1) * 3 + ((ez >> 1) + 1);
                const int slot = ((ex & 1) << 2) + ((ey & 1) << 1) + (ez & 1);
                int r = r27[ptap];
                v[o] = (r >= 0) ? slot * NPAR + r : -1;
            }
            int4* dst = (int4*)&idx_tab[k * NCH + p * 8];
            dst[0] = make_int4(v[0], v[1], v[2], v[3]);
            dst[1] = make_int4(v[4], v[5], v[6], v[7]);
        }
    } else if (b < 248) {
        int rem = (b - 32) * 256 + threadIdx.x;   // < 55296
        int lane = rem & 63;
        int ks   = (rem >> 6) & 3;
        int nb   = (rem >> 8) & 7;
        int tap  = rem >> 11;                       // 0..26
        int n  = nb * 16 + (lane & 15);
        int k0 = ks * 32 + (lane >> 4) * 8;
        unsigned short v[8];
#pragma unroll
        for (int j = 0; j < 8; ++j) v[j] = f2bf(W2[tap * 16384 + (k0 + j) * 128 + n]);
        uint4 pk;
        pk.x = (unsigned)v[0] | ((unsigned)v[1] << 16);
        pk.y = (unsigned)v[2] | ((unsigned)v[3] << 16);
        pk.z = (unsigned)v[4] | ((unsigned)v[5] << 16);
        pk.w = (unsigned)v[6] | ((unsigned)v[7] << 16);
        *(uint4*)&Wp2[(long)rem * 8] = pk;
    } else if (b < 760) {
        int rem = (b - 248) * 256 + threadIdx.x;   // < 131072
        int lane  = rem & 63;
        int ks    = (rem >> 6) & 3;
        int nb    = (rem >> 8) & 7;
        int combo = rem >> 11;                      // 0..63 = o*8+s
        int o = combo >> 3, s = combo & 7;
        int n  = nb * 16 + (lane & 15);
        int k0 = ks * 32 + (lane >> 4) * 8;
        int d0[2], d1[2], d2[2], n0, n1, n2;
        axis_dlist((o >> 2) & 1, (s >> 2) & 1, d0, n0);
        axis_dlist((o >> 1) & 1, (s >> 1) & 1, d1, n1);
        axis_dlist(o & 1,        s & 1,        d2, n2);
        unsigned short v[8];
#pragma unroll
        for (int j = 0; j < 8; ++j) {
            float acc = 0.0f;
            for (int a = 0; a < n0; ++a)
                for (int bb = 0; bb < n1; ++bb)
                    for (int cc = 0; cc < n2; ++cc) {
                        int kk = (d0[a] + 1) * 9 + (d1[bb] + 1) * 3 + (d2[cc] + 1);
                        acc += W1[kk * 16384 + (k0 + j) * 128 + n];
                    }
            v[j] = f2bf(acc);
        }
        uint4 pk;
        pk.x = (unsigned)v[0] | ((unsigned)v[1] << 16);
        pk.y = (unsigned)v[2] | ((unsigned)v[3] << 16);
        pk.z = (unsigned)v[4] | ((unsigned)v[5] << 16);
        pk.w = (unsigned)v[6] | ((unsigned)v[7] << 16);
        *(uint4*)&Wc1f[(long)rem * 8] = pk;
    } else {
        const float4* x4 = (const float4*)x;
        uint2* y2 = (uint2*)y;
        const float4* g4 = (const float4*)gamma;
        const float4* b4 = (const float4*)beta;
        float cnt = (float)NPAR * 4.0f;
        int total = NPAR * 32;
        for (int idx = (b - 760) * 256 + threadIdx.x; idx < total; idx += 256 * 256) {
            int c4 = idx & 31;
            float mean = sum[c4] / cnt;
            float var = sq[c4] / cnt - mean * mean;
            float rstd = rsqrtf(var + EPS);
            float4 v = x4[idx];
            float4 gm = g4[c4];
            float4 bt = b4[c4];
            float a[4] = {v.x, v.y, v.z, v.w};
            float gg[4] = {gm.x, gm.y, gm.z, gm.w};
            float bb[4] = {bt.x, bt.y, bt.z, bt.w};
            unsigned short o[4];
#pragma unroll
            for (int i = 0; i < 4; ++i) {
                float tv = (a[i] - mean) * rstd * gg[i] + bb[i];
                o[i] = f2bf(tv / (1.0f + __expf(-tv)));
            }
            uint2 pk;
            pk.x = (unsigned)o[0] | ((unsigned)o[1] << 16);
            pk.y = (unsigned)o[2] | ((unsigned)o[3] << 16);
            y2[idx] = pk;
        }
    }
}

// ---------------------------------------------------------------------------
// bf16 in -> bf16 out, in place (GN2); layout-agnostic elementwise
__global__ void gn_apply_bf16_kernel(unsigned short* __restrict__ x,
                                     const float* __restrict__ sum, const float* __restrict__ sq,
                                     const float* __restrict__ gamma, const float* __restrict__ beta,
                                     int nrows) {
    uint2* x2 = (uint2*)x;
    const float4* g4 = (const float4*)gamma;
    const float4* b4 = (const float4*)beta;
    float cnt = (float)nrows * 4.0f;
    int total = nrows * 32;
    for (int idx = blockIdx.x * blockDim.x + threadIdx.x; idx < total;
         idx += gridDim.x * blockDim.x) {
        int c4 = idx & 31;
        float mean = sum[c4] / cnt;
        float var = sq[c4] / cnt - mean * mean;
        float rstd = rsqrtf(var + EPS);
        uint2 pk = x2[idx];
        float a[4] = {bf2f((unsigned short)(pk.x & 0xffff)), bf2f((unsigned short)(pk.x >> 16)),
                      bf2f((unsigned short)(pk.y & 0xffff)), bf2f((unsigned short)(pk.y >> 16))};
        float4 gm = g4[c4];
        float4 bt = b4[c4];
        float gg[4] = {gm.x, gm.y, gm.z, gm.w};
        float bb[4] = {bt.x, bt.y, bt.z, bt.w};
        unsigned short o[4];
#pragma unroll
        for (int i = 0; i < 4; ++i) {
            float tv = (a[i] - mean) * rstd * gg[i] + bb[i];
            o[i] = f2bf(tv / (1.0f + __expf(-tv)));
        }
        pk.x = (unsigned)o[0] | ((unsigned)o[1] << 16);
        pk.y = (unsigned)o[2] | ((unsigned)o[3] << 16);
        x2[idx] = pk;
    }
}

// ---------------------------------------------------------------------------
// Shared MFMA helpers — 1M x 4N wave grid: each wave computes ALL 128 rows x
// a distinct 32-col quarter (wn = wv).  B per block-tap is loaded exactly
// once (32 KB unique, no wave-pair redundancy) — 33% less vmem than the old
// 2Mx2N grid; the extra A ds_reads (each row read by 4 waves) ride on LDS BW.
//
// LDS A layout (per buffer): [grp(8)][ks(4)][r16(16)][cch(4)][8 shorts].
// Bank-conflict fix (verified: SQ_LDS_BANK_CONFLICT 3.54M -> 0): the 16B
// chunk stored at (r16, cch) holds source channels ks*32 + (cch^((r16>>1)&3))*8
// — XOR applied on the GLOBAL source address (global_load_lds writes
// linearly), undone on the ds_read side (swz = quad ^ ((l16>>1)&3)).
__device__ __forceinline__ void mfma_phase(
    const unsigned short* __restrict__ Abuf, short8 (&bfr)[2][4],
    floatx4 (&acc)[8][2], int aswz) {
#pragma unroll
    for (int ks = 0; ks < 4; ++ks) {
        short8 afr[8];
#pragma unroll
        for (int mt = 0; mt < 8; ++mt)
            afr[mt] = *(const short8*)&Abuf[(mt << 11) + (ks << 9) + aswz];
#pragma unroll
        for (int mt = 0; mt < 8; ++mt)
#pragma unroll
            for (int nt = 0; nt < 2; ++nt)
                acc[mt][nt] = __builtin_amdgcn_mfma_f32_16x16x32_bf16(
                    afr[mt], bfr[nt][ks], acc[mt][nt], 0, 0, 0);
    }
}
// B frags for this wave's 32-col quarter: col groups g = wn*2+nt (16 cols each)
__device__ __forceinline__ void loadB(const unsigned short* __restrict__ Wtap,
                                      short8 (&bfr)[2][4], int wn, int lane) {
#pragma unroll
    for (int nt = 0; nt < 2; ++nt)
#pragma unroll
        for (int ks = 0; ks < 4; ++ks)
            bfr[nt][ks] = *(const short8*)&Wtap[(((wn * 2 + nt) << 2) + ks) * 512 + (lane << 3)];
}
__device__ __forceinline__ void stageA(const unsigned short* __restrict__ Ag,
                                       int iv0, int iv1, const unsigned short* zsrc,
                                       unsigned short* __restrict__ buf,
                                       int base0, int base1, int cchOff) {
    const unsigned short* g0 = (iv0 >= 0) ? Ag + (long)iv0 * 128 : zsrc;
    const unsigned short* g1 = (iv1 >= 0) ? Ag + (long)iv1 * 128 : zsrc;
#pragma unroll
    for (int i = 0; i < 4; ++i) glds16(g0 + i * 32 + cchOff, &buf[base0 + i * 512]);
#pragma unroll
    for (int i = 0; i < 4; ++i) glds16(g1 + i * 32 + cchOff, &buf[base1 + i * 512]);
}

// ---------------------------------------------------------------------------
// CONV1 FOLDED — 2x-unrolled slot loop, ping-pong B register sets (bA/bB, no
// copies), 1Mx4N wave grid.
__global__ void __launch_bounds__(256, 2) conv1_fold_kernel(
    const unsigned short* __restrict__ Ag, const unsigned short* __restrict__ Wc1f,
    const float* __restrict__ bias, const int* __restrict__ pidx27,
    unsigned short* __restrict__ outp, const float* __restrict__ zpage,
    float* __restrict__ gsum, float* __restrict__ gsq) {
    __shared__ unsigned short A_lds[2][16384];   // 2 x 32 KB

    int t = threadIdx.x;
    int o  = blockIdx.x & 7;
    int P0 = (blockIdx.x >> 3) << 7;            // 128 parents per block
    const unsigned short* Wb = Wc1f + ((long)o << 17);
    int wv = t >> 6, lane = t & 63, quad = lane >> 4, l16 = lane & 15;
    int wn = wv;                                 // 1M x 4N: wave owns 32 cols
    int r16 = lane >> 2, cch = lane & 3;
    int c0 = wv * 2, c1 = wv * 2 + 1;
    int row0 = ((c0 >> 2) << 6) + ((c0 & 3) << 4) + r16;
    int row1 = ((c1 >> 2) << 6) + ((c1 & 3) << 4) + r16;
    int base0 = ((c0 >> 2) << 13) + ((c0 & 3) << 11);
    int base1 = ((c1 >> 2) << 13) + ((c1 & 3) << 11);
    int cchOff = (cch ^ ((r16 >> 1) & 3)) << 3;            // swizzled source chunk
    int aswz = (l16 << 5) + ((quad ^ ((l16 >> 1) & 3)) << 3);  // swizzled read
    const unsigned short* zsrc = (const unsigned short*)zpage;

    floatx4 acc[8][2];
#pragma unroll
    for (int mt = 0; mt < 8; ++mt)
#pragma unroll
        for (int nt = 0; nt < 2; ++nt)
            acc[mt][nt] = (floatx4){0.f, 0.f, 0.f, 0.f};
    short8 bA[2][4], bB[2][4];

    // ---- prolog: slot 0 A -> buf0, slot 0 B -> bA
    stageA(Ag, pidx27[k27_of(o, 0) * NPAR + P0 + row0],
               pidx27[k27_of(o, 0) * NPAR + P0 + row1], zsrc, A_lds[0], base0, base1, cchOff);
    loadB(Wb, bA, wn, lane);
    int nv0 = pidx27[k27_of(o, 1) * NPAR + P0 + row0];
    int nv1 = pidx27[k27_of(o, 1) * NPAR + P0 + row1];
    __syncthreads();

#pragma unroll 1
    for (int s = 0; s < 8; s += 2) {
        // phase A: slot s from buf0/bA; stage slot s+1 -> buf1, B(s+1) -> bB
        stageA(Ag, nv0, nv1, zsrc, A_lds[1], base0, base1, cchOff);
        loadB(Wb + ((long)(s + 1) << 14), bB, wn, lane);
        if (s + 2 < 8) {
            nv0 = pidx27[k27_of(o, s + 2) * NPAR + P0 + row0];
            nv1 = pidx27[k27_of(o, s + 2) * NPAR + P0 + row1];
        }
        mfma_phase(A_lds[0], bA, acc, aswz);
        __syncthreads();
        // phase B: slot s+1 from buf1/bB; stage slot s+2 -> buf0, B(s+2) -> bA
        if (s + 2 < 8) {
            stageA(Ag, nv0, nv1, zsrc, A_lds[0], base0, base1, cchOff);
            loadB(Wb + ((long)(s + 2) << 14), bA, wn, lane);
            if (s + 3 < 8) {
                nv0 = pidx27[k27_of(o, s + 3) * NPAR + P0 + row0];
                nv1 = pidx27[k27_of(o, s + 3) * NPAR + P0 + row1];
            }
        }
        mfma_phase(A_lds[1], bB, acc, aswz);
        __syncthreads();
    }

    // ---- epilogue: coalesced bf16 store at row o*NPAR + p, fused GN2 stats
    float s_[2] = {0.f, 0.f}, q_[2] = {0.f, 0.f};
#pragma unroll
    for (int nt = 0; nt < 2; ++nt) {
        int col = wn * 32 + nt * 16 + l16;
        float bv = bias[col];
#pragma unroll
        for (int mt = 0; mt < 8; ++mt) {
#pragma unroll
            for (int r = 0; r < 4; ++r) {
                int prow = mt * 16 + quad * 4 + r;
                long R = (long)o * NPAR + P0 + prow;
                float v = acc[mt][nt][r] + bv;
                unsigned short u = f2bf(v);
                outp[R * 128 + col] = u;
                float vr = bf2f(u);
                s_[nt] += vr;
                q_[nt] += vr * vr;
            }
        }
    }
    float* sred = (float*)A_lds;   // safe: loop's trailing barrier passed
    if (t < 64) sred[t] = 0.0f;
    __syncthreads();
#pragma unroll
    for (int nt = 0; nt < 2; ++nt) {
        int g = (wn * 32 + nt * 16 + l16) >> 2;
        atomicAdd(&sred[g], s_[nt]);
        atomicAdd(&sred[32 + g], q_[nt]);
    }
    __syncthreads();
    if (t < 32) { atomicAdd(&gsum[t], sred[t]); atomicAdd(&gsq[t], sred[32 + t]); }
}

// ---------------------------------------------------------------------------
// CONV2 — 2x-unrolled tap loop, ping-pong B register sets, 1Mx4N wave grid.
__global__ void __launch_bounds__(256, 2) conv2_kernel(
    const unsigned short* __restrict__ Ag, const unsigned short* __restrict__ Wp,
    const float* __restrict__ bias, const int* __restrict__ idx_tab,
    const float* __restrict__ resid, float* __restrict__ outp,
    const float* __restrict__ zpage) {
    __shared__ unsigned short A_lds[2][16384];   // 2 x 32 KB

    int t = threadIdx.x;
    int R0 = blockIdx.x * 128;
    int wv = t >> 6, lane = t & 63, quad = lane >> 4, l16 = lane & 15;
    int wn = wv;                                 // 1M x 4N: wave owns 32 cols
    int r16 = lane >> 2, cch = lane & 3;
    int c0 = wv * 2, c1 = wv * 2 + 1;
    int row0 = ((c0 >> 2) << 6) + ((c0 & 3) << 4) + r16;
    int row1 = ((c1 >> 2) << 6) + ((c1 & 3) << 4) + r16;
    int base0 = ((c0 >> 2) << 13) + ((c0 & 3) << 11);
    int base1 = ((c1 >> 2) << 13) + ((c1 & 3) << 11);
    int cchOff = (cch ^ ((r16 >> 1) & 3)) << 3;            // swizzled source chunk
    int aswz = (l16 << 5) + ((quad ^ ((l16 >> 1) & 3)) << 3);  // swizzled read
    const unsigned short* zsrc = (const unsigned short*)zpage;

    floatx4 acc[8][2];
#pragma unroll
    for (int mt = 0; mt < 8; ++mt)
#pragma unroll
        for (int nt = 0; nt < 2; ++nt)
            acc[mt][nt] = (floatx4){0.f, 0.f, 0.f, 0.f};
    short8 bA[2][4], bB[2][4];

    // ---- prolog: tap 0 A -> buf0, tap 0 B -> bA
    stageA(Ag, idx_tab[R0 + row0], idx_tab[R0 + row1], zsrc, A_lds[0], base0, base1, cchOff);
    loadB(Wp, bA, wn, lane);
    int nv0 = idx_tab[NCH + R0 + row0], nv1 = idx_tab[NCH + R0 + row1];
    __syncthreads();

#pragma unroll 1
    for (int k = 0; k < 27; k += 2) {
        // phase A: tap k from buf0/bA
        if (k + 1 < 27) {
            stageA(Ag, nv0, nv1, zsrc, A_lds[1], base0, base1, cchOff);
            loadB(Wp + ((long)(k + 1) << 14), bB, wn, lane);
            if (k + 2 < 27) {
                nv0 = idx_tab[(k + 2) * NCH + R0 + row0];
                nv1 = idx_tab[(k + 2) * NCH + R0 + row1];
            }
        }
        mfma_phase(A_lds[0], bA, acc, aswz);
        __syncthreads();
        // phase B: tap k+1 from buf1/bB
        if (k + 1 < 27) {
            if (k + 2 < 27) {
                stageA(Ag, nv0, nv1, zsrc, A_lds[0], base0, base1, cchOff);
                loadB(Wp + ((long)(k + 2) << 14), bA, wn, lane);
                if (k + 3 < 27) {
                    nv0 = idx_tab[(k + 3) * NCH + R0 + row0];
                    nv1 = idx_tab[(k + 3) * NCH + R0 + row1];
                }
            }
            mfma_phase(A_lds[1], bB, acc, aswz);
            __syncthreads();
        }
    }

#pragma unroll
    for (int nt = 0; nt < 2; ++nt) {
        int col = wn * 32 + nt * 16 + l16;
        float bv = bias[col];
#pragma unroll
        for (int mt = 0; mt < 8; ++mt) {
#pragma unroll
            for (int r = 0; r < 4; ++r) {
                int row = mt * 16 + quad * 4 + r;
                long R = (long)R0 + row;
                float v = acc[mt][nt][r] + bv + resid[(R >> 3) * 128 + col];
                outp[R * 128 + col] = v;
            }
        }
    }
}

// ---------------------------------------------------------------------------
extern "C" void kernel_launch(void* const* d_in, const int* in_sizes, int n_in,
                              void* d_out, int out_size, void* d_ws, size_t ws_size,
                              hipStream_t stream) {
    const float* feats  = (const float*)d_in[0];
    const float* gamma1 = (const float*)d_in[1];
    const float* beta1  = (const float*)d_in[2];
    const float* W1     = (const float*)d_in[3];
    const float* b1     = (const float*)d_in[4];
    const float* gamma2 = (const float*)d_in[5];
    const float* beta2  = (const float*)d_in[6];
    const float* W2     = (const float*)d_in[7];
    const float* b2     = (const float*)d_in[8];
    const int*   coords = (const int*)d_in[9];
    float* out = (float*)d_out;   // 65536 x 128 fp32 (written only by conv2)

    char* ws = (char*)d_ws;
    unsigned short* h0b  = (unsigned short*)(ws);                    // 2 MB
    unsigned short* h1b  = (unsigned short*)(ws + (2u << 20));       // 16 MB, (o,p) layout
    unsigned short* Wc1f = (unsigned short*)(ws + (18u << 20));      // 2 MB
    unsigned short* Wp2  = (unsigned short*)(ws + (20u << 20));      // 864 KB
    int*   grid32        = (int*)  (ws + (21u << 20));               // 128 KB
    float* stats         = (float*)(ws + (21u << 20) + 131072);      // 512 B
    float* zpage         = (float*)(ws + (21u << 20) + 131072 + 512);// 512 B
    int*   idx_tab       = (int*)  (ws + (22u << 20));               // 7.08 MB
    int*   pidx27        = (int*)  (ws + (30u << 20));               // 864 KB

    // zero stats (128 f) + zpage (128 f) in one async memset
    hipMemsetAsync(stats, 0, 1024, stream);

    k1_kernel<<<288, 256, 0, stream>>>(coords, grid32, feats, stats + 0, stats + 32);
    k2_kernel<<<1016, 256, 0, stream>>>(coords, grid32, idx_tab, pidx27,
                                        W1, W2, Wc1f, Wp2,
                                        feats, stats + 0, stats + 32, gamma1, beta1, h0b);

    // conv1 folded -> bf16 h1b in (o,p) layout + fused GN2 stats
    conv1_fold_kernel<<<8 * (NPAR / 128), 256, 0, stream>>>(h0b, Wc1f, b1, pidx27,
                                                            h1b, zpage,
                                                            stats + 64, stats + 96);

    gn_apply_bf16_kernel<<<1024, 256, 0, stream>>>(h1b, stats + 64, stats + 96, gamma2, beta2, NCH);

    // conv2 (27 taps over children) -> fp32 out + residual repeat(feats,8)
    conv2_kernel<<<NCH / 128, 256, 0, stream>>>(h1b, Wp2, b2, idx_tab,
                                                feats, out, zpage);
}